// Round 5
// baseline (553.847 us; speedup 1.0000x reference)
//
#include <hip/hip_runtime.h>
#include <hip/hip_bf16.h>

// SpatialWindowSelfAttention — MI355X gfx950.
// v5: v4 + (a) V computed in flipped MFMA orientation (A=x, B=wv) so PV runs as
// O^T = V^T P^T with BOTH operands built by the register pack2+shfl transform —
// the LDS Vt buffer and its transposed writes are deleted (LDS 52.2->33.8 KB);
// (b) all LDS fragment reads are single ds_read_b128 (two-b64 lds8 put 8 lanes
// on one bank-pair = 8.1M conflicts; b128 hits the bank floor); (c) primary
// kernel at __launch_bounds__(256,3) for 3 blocks/CU, with a RUNTIME spill
// guard: if hipFuncGetAttributes reports localSizeBytes!=0 (the R1/R2 spill
// disease), launch the plain-bounds twin instead.
// Fallback path (ws too small): previous verified two-kernel version.

typedef __bf16 bf16;
typedef bf16 bf16x2 __attribute__((ext_vector_type(2)));
typedef bf16 bf16x4 __attribute__((ext_vector_type(4)));
typedef bf16 bf16x8 __attribute__((ext_vector_type(8)));
typedef float f32x4 __attribute__((ext_vector_type(4)));
typedef int i32x2 __attribute__((ext_vector_type(2)));
typedef int i32x4 __attribute__((ext_vector_type(4)));

#define MFMA16(a, b, c) __builtin_amdgcn_mfma_f32_16x16x32_bf16(a, b, c, 0, 0, 0)

__device__ __forceinline__ bf16x8 cvt8(const float* p) {  // 32B-aligned f32 -> bf16x8
  f32x4 lo = *(const f32x4*)p;
  f32x4 hi = *(const f32x4*)(p + 4);
  bf16x8 r;
#pragma unroll
  for (int j = 0; j < 4; j++) { r[j] = (bf16)lo[j]; r[j + 4] = (bf16)hi[j]; }
  return r;
}
__device__ __forceinline__ bf16x8 lds8(const bf16* p) {  // legacy 2xb64 (fallback path)
  bf16x4 lo = *(const bf16x4*)p;
  bf16x4 hi = *(const bf16x4*)(p + 4);
  return __builtin_shufflevector(lo, hi, 0, 1, 2, 3, 4, 5, 6, 7);
}
__device__ __forceinline__ int pack2(float a, float b) {  // 2 f32 -> bf16x2 dword
  bf16x2 t; t[0] = (bf16)a; t[1] = (bf16)b;
  return __builtin_bit_cast(int, t);
}

// C-layout -> A/B-frag transform (verified in v3/v4): dest lane (quad,lr) word w
// takes packed (r0,r1)/(r2,r3) pairs from source lane L0/L1 of tile lo/hi.
__device__ __forceinline__ bf16x8 frag_xpose(int aLo, int bLo, int aHi, int bHi,
                                             int L0, int L1, bool hiq) {
  const int a0 = __shfl(aLo, L0, 64), a1 = __shfl(aHi, L0, 64);
  const int b0 = __shfl(bLo, L0, 64), b1 = __shfl(bHi, L0, 64);
  const int a0h = __shfl(aLo, L1, 64), a1h = __shfl(aHi, L1, 64);
  const int b0h = __shfl(bLo, L1, 64), b1h = __shfl(bHi, L1, 64);
  const i32x4 w = {hiq ? a1 : a0, hiq ? b1 : b0, hiq ? a1h : a0h, hiq ? b1h : b0h};
  return __builtin_bit_cast(bf16x8, w);
}

// ======================= FAST PATH (v5) =======================

// K0: permute+convert weights into MFMA-fragment order.
__global__ __launch_bounds__(256) void cvt_weights_v3(
    const float* __restrict__ wq, const float* __restrict__ wp, bf16* __restrict__ dst) {
  const int did = blockIdx.x * 256 + threadIdx.x;  // [0, 32768)
  const float* src;
  bf16* o;
  if (did < 24576) {
    const int ct = did >> 9, rem = did & 511, kb = rem >> 6, ln = rem & 63;
    src = wq + (size_t)(ct * 16 + (ln & 15)) * 256 + kb * 32 + (ln >> 4) * 8;
    o = dst + (size_t)did * 8;
  } else {
    const int d2 = did - 24576;
    const int ct = d2 >> 9, rem = d2 & 511, kb = rem >> 6, ln = rem & 63;
    src = wp + (size_t)(ct * 16 + (ln & 15)) * 256 + kb * 32 + (ln >> 4) * 8;
    o = dst + 196608 + (size_t)d2 * 8;
  }
  *(bf16x8*)o = cvt8(src);
}

// Per-head: QKV proj + attention, zero LDS scratch, y packed into ob[16]
// (layout: ob[(dt*4+qt)*2 + w], O^T orientation: d on (quad,r), qtok on lr).
__device__ __forceinline__ void attn_head_v5(
    const int h, const int lane, const int lr, const int quad,
    const bf16 (*__restrict__ xs)[264],
    const bf16* __restrict__ wqf, const float* __restrict__ wqkv_b,
    const float* __restrict__ bias_table, int* __restrict__ ob) {
  const f32x4 zero = {0.f, 0.f, 0.f, 0.f};
  const float scale = 0.17677669529663687f;  // 1/sqrt(32)
  const int L0 = ((quad & 1) << 5) | lr, L1 = L0 + 16;
  const bool hiq = quad >= 2;

  // ---- pass 1: Q (mi 0,1) + K (mi 2,3); A = wqkv rows, B = x frags ----
  f32x4 acc[4][4] = {};
  const int ctq = 2 * h, ctk = 16 + 2 * h;
#pragma unroll
  for (int kb = 0; kb < 8; ++kb) {
    bf16x8 b[4];
#pragma unroll
    for (int nj = 0; nj < 4; ++nj)
      b[nj] = *(const bf16x8*)&xs[nj * 16 + lr][kb * 32 + quad * 8];
#pragma unroll
    for (int mi = 0; mi < 4; ++mi) {
      const int ct = (mi < 2) ? (ctq + mi) : (ctk + mi - 2);
      const bf16x8 a = *(const bf16x8*)&wqf[(size_t)((ct * 8 + kb) * 64 + lane) * 8];
#pragma unroll
      for (int nj = 0; nj < 4; ++nj) acc[mi][nj] = MFMA16(a, b[nj], acc[mi][nj]);
    }
  }
  // bias (ch on quad*4+r)
#pragma unroll
  for (int mi = 0; mi < 4; ++mi) {
    const int cb = (mi < 2) ? (h * 32 + mi * 16) : (256 + h * 32 + (mi - 2) * 16);
    const f32x4 bb = *(const f32x4*)&wqkv_b[cb + quad * 4];
#pragma unroll
    for (int nj = 0; nj < 4; ++nj)
#pragma unroll
      for (int r = 0; r < 4; ++r) acc[mi][nj][r] += bb[r];
  }
  // ---- qf/kf: (qtok on lr stays; d moves (quad,r)->(quad,j)) ----
  bf16x8 qf[4], kf[4];
#pragma unroll
  for (int t = 0; t < 4; ++t) {
    qf[t] = frag_xpose(pack2(acc[0][t][0], acc[0][t][1]), pack2(acc[0][t][2], acc[0][t][3]),
                       pack2(acc[1][t][0], acc[1][t][1]), pack2(acc[1][t][2], acc[1][t][3]),
                       L0, L1, hiq);
    kf[t] = frag_xpose(pack2(acc[2][t][0], acc[2][t][1]), pack2(acc[2][t][2], acc[2][t][3]),
                       pack2(acc[3][t][0], acc[3][t][1]), pack2(acc[3][t][2], acc[3][t][3]),
                       L0, L1, hiq);
  }
  // ---- S^T = K Q^T : ktok = kt*16+quad*4+r, qtok = qt*16+lr ----
  f32x4 s[4][4];
#pragma unroll
  for (int kt = 0; kt < 4; ++kt)
#pragma unroll
    for (int qt = 0; qt < 4; ++qt) s[kt][qt] = MFMA16(kf[kt], qf[qt], zero);
#pragma unroll
  for (int kt = 0; kt < 4; ++kt)
#pragma unroll
    for (int r = 0; r < 4; ++r) {
      const int ktok = kt * 16 + quad * 4 + r;
#pragma unroll
      for (int qt = 0; qt < 4; ++qt) {
        const int qtok = qt * 16 + lr;
        const int idx = ((qtok >> 3) - (ktok >> 3) + 7) * 15 + (qtok & 7) - (ktok & 7) + 7;
        s[kt][qt][r] = s[kt][qt][r] * scale + bias_table[idx * 8 + h];
      }
    }
  // ---- softmax over k (16 in-lane + 2 cross-quad shuffles per q) ----
  float inv[4];
#pragma unroll
  for (int qt = 0; qt < 4; ++qt) {
    float mx = -1e30f;
#pragma unroll
    for (int kt = 0; kt < 4; ++kt)
#pragma unroll
      for (int r = 0; r < 4; ++r) mx = fmaxf(mx, s[kt][qt][r]);
    mx = fmaxf(mx, __shfl_xor(mx, 16, 64));
    mx = fmaxf(mx, __shfl_xor(mx, 32, 64));
    float sum = 0.f;
#pragma unroll
    for (int kt = 0; kt < 4; ++kt)
#pragma unroll
      for (int r = 0; r < 4; ++r) {
        const float e = __expf(s[kt][qt][r] - mx);
        s[kt][qt][r] = e;
        sum += e;
      }
    sum += __shfl_xor(sum, 16, 64);
    sum += __shfl_xor(sum, 32, 64);
    inv[qt] = 1.0f / sum;
  }
  // ---- pb (B-frag P^T: n=qtok on lr, k=ktok on quad*8+j) ----
  bf16x8 pb[4][2];
#pragma unroll
  for (int qt = 0; qt < 4; ++qt)
#pragma unroll
    for (int kq = 0; kq < 2; ++kq)
      pb[qt][kq] = frag_xpose(
          pack2(s[2 * kq][qt][0] * inv[qt], s[2 * kq][qt][1] * inv[qt]),
          pack2(s[2 * kq][qt][2] * inv[qt], s[2 * kq][qt][3] * inv[qt]),
          pack2(s[2 * kq + 1][qt][0] * inv[qt], s[2 * kq + 1][qt][1] * inv[qt]),
          pack2(s[2 * kq + 1][qt][2] * inv[qt], s[2 * kq + 1][qt][3] * inv[qt]),
          L0, L1, hiq);
  // ---- pass 2: V flipped: A = x frag (m=tok), B = wv (n=d) ----
  f32x4 av[4][2] = {};
  const int ctv = 32 + 2 * h;
#pragma unroll
  for (int kb = 0; kb < 8; ++kb) {
    bf16x8 b[4];
#pragma unroll
    for (int nj = 0; nj < 4; ++nj)
      b[nj] = *(const bf16x8*)&xs[nj * 16 + lr][kb * 32 + quad * 8];
#pragma unroll
    for (int mi = 0; mi < 2; ++mi) {
      const bf16x8 a = *(const bf16x8*)&wqf[(size_t)(((ctv + mi) * 8 + kb) * 64 + lane) * 8];
#pragma unroll
      for (int nj = 0; nj < 4; ++nj) av[nj][mi] = MFMA16(b[nj], a, av[nj][mi]);
    }
  }
  // V bias (d on lr now)
#pragma unroll
  for (int dt = 0; dt < 2; ++dt) {
    const float bv = wqkv_b[512 + h * 32 + dt * 16 + lr];
#pragma unroll
    for (int t = 0; t < 4; ++t)
#pragma unroll
      for (int r = 0; r < 4; ++r) av[t][dt][r] += bv;
  }
  // ---- O^T = V^T P^T : va (A-frag: m=d on lr, k=tok on quad*8+j) in-register ----
  f32x4 o[2][4] = {};
#pragma unroll
  for (int kq = 0; kq < 2; ++kq) {
    bf16x8 va[2];
#pragma unroll
    for (int dt = 0; dt < 2; ++dt)
      va[dt] = frag_xpose(
          pack2(av[2 * kq][dt][0], av[2 * kq][dt][1]), pack2(av[2 * kq][dt][2], av[2 * kq][dt][3]),
          pack2(av[2 * kq + 1][dt][0], av[2 * kq + 1][dt][1]),
          pack2(av[2 * kq + 1][dt][2], av[2 * kq + 1][dt][3]), L0, L1, hiq);
#pragma unroll
    for (int dt = 0; dt < 2; ++dt)
#pragma unroll
      for (int qt = 0; qt < 4; ++qt) o[dt][qt] = MFMA16(va[dt], pb[qt][kq], o[dt][qt]);
  }
  // pack O^T: d = dt*16+quad*4+r, qtok = qt*16+lr
#pragma unroll
  for (int dt = 0; dt < 2; ++dt)
#pragma unroll
    for (int qt = 0; qt < 4; ++qt) {
      ob[(dt * 4 + qt) * 2 + 0] = pack2(o[dt][qt][0], o[dt][qt][1]);
      ob[(dt * 4 + qt) * 2 + 1] = pack2(o[dt][qt][2], o[dt][qt][3]);
    }
}

__device__ __forceinline__ void swin_v5_body(
    bf16 (*__restrict__ xs)[264],
    const float* __restrict__ x, const bf16* __restrict__ wqf,
    const float* __restrict__ wqkv_b, const float* __restrict__ bias_table,
    const bf16* __restrict__ wpf, const float* __restrict__ wp_b,
    float* __restrict__ out) {
  const int tid = threadIdx.x;
  const int wave = tid >> 6, lane = tid & 63;
  const int lr = lane & 15, quad = lane >> 4;
  const int win = blockIdx.x;  // [0,2048)
  const int batch = win >> 10, wy = (win >> 5) & 31, wx = win & 31;
  const int base = batch * 65536 + wy * 2048 + wx * 8;

  // ---- stage full x window [64 tok][256 ch] f32 -> bf16 ----
  {
    const int tok = tid >> 2, cg = (tid & 3) * 64;
    const float* xp = x + (size_t)(base + ((tok >> 3) << 8) + (tok & 7)) * 256 + cg;
#pragma unroll
    for (int g = 0; g < 8; ++g) *(bf16x8*)&xs[tok][cg + g * 8] = cvt8(xp + g * 8);
  }
  __syncthreads();  // barrier 1

  int ob0[16], ob1[16];
  attn_head_v5(wave * 2 + 0, lane, lr, quad, (const bf16(*)[264])xs, wqf, wqkv_b, bias_table, ob0);
  attn_head_v5(wave * 2 + 1, lane, lr, quad, (const bf16(*)[264])xs, wqf, wqkv_b, bias_table, ob1);

  __syncthreads();  // barrier 2: all waves done reading x
  // ---- y (bf16) into xs[tok][ch]; O^T layout -> vectorized 8B stores ----
#pragma unroll
  for (int rep = 0; rep < 2; ++rep) {
    const int* ob = rep ? ob1 : ob0;
    const int hh = wave * 2 + rep;
#pragma unroll
    for (int dt = 0; dt < 2; ++dt)
#pragma unroll
      for (int qt = 0; qt < 4; ++qt) {
        const i32x2 v = {ob[(dt * 4 + qt) * 2], ob[(dt * 4 + qt) * 2 + 1]};
        *(i32x2*)&xs[qt * 16 + lr][hh * 32 + dt * 16 + quad * 4] = v;
      }
  }
  __syncthreads();  // barrier 3: y complete
  // ---- output projection: out = y @ wp^T + b; wave owns 64 cols ----
  f32x4 ap[4][4] = {};
#pragma unroll
  for (int kb = 0; kb < 8; ++kb) {
    bf16x8 a[4], b[4];
#pragma unroll
    for (int mt = 0; mt < 4; ++mt)
      a[mt] = *(const bf16x8*)&xs[mt * 16 + lr][kb * 32 + quad * 8];
#pragma unroll
    for (int nt = 0; nt < 4; ++nt)
      b[nt] = *(const bf16x8*)&wpf[(size_t)(((wave * 4 + nt) * 8 + kb) * 64 + lane) * 8];
#pragma unroll
    for (int mt = 0; mt < 4; ++mt)
#pragma unroll
      for (int nt = 0; nt < 4; ++nt) ap[mt][nt] = MFMA16(a[mt], b[nt], ap[mt][nt]);
  }
#pragma unroll
  for (int nt = 0; nt < 4; ++nt) {
    const int col = (wave * 4 + nt) * 16 + lr;
    const float bv = wp_b[col];
#pragma unroll
    for (int mt = 0; mt < 4; ++mt)
#pragma unroll
      for (int r = 0; r < 4; ++r) {
        const int t = mt * 16 + quad * 4 + r;
        const size_t grow = (size_t)(base + ((t >> 3) << 8) + (t & 7));
        out[grow * 256 + col] = ap[mt][nt][r] + bv;
      }
  }
}

__global__ __launch_bounds__(256, 3) void swin_v5_hi(
    const float* __restrict__ x, const bf16* __restrict__ wqf,
    const float* __restrict__ wqkv_b, const float* __restrict__ bias_table,
    const bf16* __restrict__ wpf, const float* __restrict__ wp_b,
    float* __restrict__ out) {
  __shared__ __align__(16) bf16 xs[64][264];
  swin_v5_body(xs, x, wqf, wqkv_b, bias_table, wpf, wp_b, out);
}

__global__ __launch_bounds__(256) void swin_v5_lo(
    const float* __restrict__ x, const bf16* __restrict__ wqf,
    const float* __restrict__ wqkv_b, const float* __restrict__ bias_table,
    const bf16* __restrict__ wpf, const float* __restrict__ wp_b,
    float* __restrict__ out) {
  __shared__ __align__(16) bf16 xs[64][264];
  swin_v5_body(xs, x, wqf, wqkv_b, bias_table, wpf, wp_b, out);
}

// ======================= FALLBACK PATH (previous verified kernels) =======================

#define QS_OFF 0
#define KS_OFF 2304
#define VT_OFF 4608
#define PL_OFF 0
#define UNI_SZ 6784

__global__ __launch_bounds__(256) void fused_qkv_attn(
    const float* __restrict__ x, const float* __restrict__ wqkv_w,
    const float* __restrict__ wqkv_b, const float* __restrict__ bias_table,
    float* __restrict__ out) {
  __shared__ bf16 xs[64][72];
  __shared__ bf16 uni[4][UNI_SZ];

  const int tid = threadIdx.x;
  const int wave = tid >> 6, lane = tid & 63;
  const int lr = lane & 15, quad = lane >> 4;
  const int win = blockIdx.x;
  const int batch = win >> 10, wy = (win >> 5) & 31, wx = win & 31;
  const int base = batch * 65536 + wy * 2048 + wx * 8;
  bf16* const U = &uni[wave][0];

  const f32x4 zero = {0.f, 0.f, 0.f, 0.f};
  const float scale = 0.17677669529663687f;

  for (int rep = 0; rep < 2; rep++) {
    const int h = wave * 2 + rep;
    const int cb[6] = {h * 32,       h * 32 + 16,
                       256 + h * 32, 256 + h * 32 + 16,
                       512 + h * 32, 512 + h * 32 + 16};

    f32x4 acc[4][6] = {};
    for (int kc = 0; kc < 4; kc++) {
      __syncthreads();
      {
        const int t = tid >> 2, c0 = (tid & 3) * 16;
        const float* xp = x + (size_t)(base + (t >> 3) * 256 + (t & 7)) * 256 + kc * 64 + c0;
        *(bf16x8*)&xs[t][c0] = cvt8(xp);
        *(bf16x8*)&xs[t][c0 + 8] = cvt8(xp + 8);
      }
      __syncthreads();
#pragma unroll
      for (int k2 = 0; k2 < 64; k2 += 32) {
        bf16x8 a[4], b[6];
#pragma unroll
        for (int mi = 0; mi < 4; mi++) a[mi] = lds8(&xs[mi * 16 + lr][k2 + quad * 8]);
#pragma unroll
        for (int nj = 0; nj < 6; nj++)
          b[nj] = cvt8(wqkv_w + (size_t)(cb[nj] + lr) * 256 + kc * 64 + k2 + quad * 8);
#pragma unroll
        for (int mi = 0; mi < 4; mi++)
#pragma unroll
          for (int nj = 0; nj < 6; nj++) acc[mi][nj] = MFMA16(a[mi], b[nj], acc[mi][nj]);
      }
    }

#pragma unroll
    for (int nj = 0; nj < 6; nj++) {
      const float bv = wqkv_b[cb[nj] + lr];
#pragma unroll
      for (int mi = 0; mi < 4; mi++)
#pragma unroll
        for (int r = 0; r < 4; r++) {
          const int tok = mi * 16 + quad * 4 + r;
          const float v = acc[mi][nj][r] + bv;
          if (nj < 2)      U[QS_OFF + tok * 36 + nj * 16 + lr] = (bf16)v;
          else if (nj < 4) U[KS_OFF + tok * 36 + (nj - 2) * 16 + lr] = (bf16)v;
          else             U[VT_OFF + ((nj - 4) * 16 + lr) * 68 + tok] = (bf16)v;
        }
    }

    bf16x8 qf[4], kf[4];
#pragma unroll
    for (int i = 0; i < 4; i++) {
      qf[i] = lds8(&U[QS_OFF + (i * 16 + lr) * 36 + quad * 8]);
      kf[i] = lds8(&U[KS_OFF + (i * 16 + lr) * 36 + quad * 8]);
    }
    f32x4 s[4][4];
#pragma unroll
    for (int mi = 0; mi < 4; mi++)
#pragma unroll
      for (int nj = 0; nj < 4; nj++) s[mi][nj] = MFMA16(qf[mi], kf[nj], zero);

#pragma unroll
    for (int mi = 0; mi < 4; mi++)
#pragma unroll
      for (int nj = 0; nj < 4; nj++)
#pragma unroll
        for (int r = 0; r < 4; r++) {
          const int qt = mi * 16 + quad * 4 + r;
          const int kt = nj * 16 + lr;
          const int idx = ((qt >> 3) - (kt >> 3) + 7) * 15 + ((qt & 7) - (kt & 7) + 7);
          s[mi][nj][r] = s[mi][nj][r] * scale + bias_table[idx * 8 + h];
        }

#pragma unroll
    for (int mi = 0; mi < 4; mi++)
#pragma unroll
      for (int r = 0; r < 4; r++) {
        float mx = -1e30f;
#pragma unroll
        for (int nj = 0; nj < 4; nj++) mx = fmaxf(mx, s[mi][nj][r]);
#pragma unroll
        for (int off = 1; off < 16; off <<= 1) mx = fmaxf(mx, __shfl_xor(mx, off, 64));
        float sum = 0.f;
#pragma unroll
        for (int nj = 0; nj < 4; nj++) {
          const float e = __expf(s[mi][nj][r] - mx);
          s[mi][nj][r] = e;
          sum += e;
        }
#pragma unroll
        for (int off = 1; off < 16; off <<= 1) sum += __shfl_xor(sum, off, 64);
        const float inv = 1.0f / sum;
#pragma unroll
        for (int nj = 0; nj < 4; nj++)
          U[PL_OFF + (mi * 16 + quad * 4 + r) * 68 + nj * 16 + lr] = (bf16)(s[mi][nj][r] * inv);
      }

    f32x4 o[4][2] = {};
#pragma unroll
    for (int kq = 0; kq < 2; kq++) {
      bf16x8 pa[4], vb[2];
#pragma unroll
      for (int mi = 0; mi < 4; mi++)
        pa[mi] = lds8(&U[PL_OFF + (mi * 16 + lr) * 68 + kq * 32 + quad * 8]);
#pragma unroll
      for (int ni = 0; ni < 2; ni++)
        vb[ni] = lds8(&U[VT_OFF + (ni * 16 + lr) * 68 + kq * 32 + quad * 8]);
#pragma unroll
      for (int mi = 0; mi < 4; mi++)
#pragma unroll
        for (int ni = 0; ni < 2; ni++) o[mi][ni] = MFMA16(pa[mi], vb[ni], o[mi][ni]);
    }

#pragma unroll
    for (int mi = 0; mi < 4; mi++)
#pragma unroll
      for (int ni = 0; ni < 2; ni++)
#pragma unroll
        for (int r = 0; r < 4; r++) {
          const int t = mi * 16 + quad * 4 + r;
          const size_t row = (size_t)(base + (t >> 3) * 256 + (t & 7));
          out[row * 256 + h * 32 + ni * 16 + lr] = o[mi][ni][r];
        }
  }
}

__global__ __launch_bounds__(256) void proj_inplace(
    float* io, const float* __restrict__ W, const float* __restrict__ bias) {
  const int tid = threadIdx.x;
  const int wave = tid >> 6, lane = tid & 63;
  const int lr = lane & 15, quad = lane >> 4;
  const int row0 = blockIdx.x * 128 + (wave >> 1) * 64;
  const int col0 = (wave & 1) * 128;

  f32x4 acc[4][8] = {};
#pragma unroll
  for (int kk = 0; kk < 256; kk += 32) {
    bf16x8 a[4], b[8];
#pragma unroll
    for (int mi = 0; mi < 4; mi++)
      a[mi] = cvt8(io + (size_t)(row0 + mi * 16 + lr) * 256 + kk + quad * 8);
#pragma unroll
    for (int nj = 0; nj < 8; nj++)
      b[nj] = cvt8(W + (size_t)(col0 + nj * 16 + lr) * 256 + kk + quad * 8);
#pragma unroll
    for (int mi = 0; mi < 4; mi++)
#pragma unroll
      for (int nj = 0; nj < 8; nj++) acc[mi][nj] = MFMA16(a[mi], b[nj], acc[mi][nj]);
  }
  __syncthreads();
#pragma unroll
  for (int mi = 0; mi < 4; mi++)
#pragma unroll
    for (int nj = 0; nj < 8; nj++) {
      const int col = col0 + nj * 16 + lr;
      const float bv = bias[col];
#pragma unroll
      for (int r = 0; r < 4; r++) {
        const int row = row0 + mi * 16 + quad * 4 + r;
        io[(size_t)row * 256 + col] = acc[mi][nj][r] + bv;
      }
    }
}

extern "C" void kernel_launch(void* const* d_in, const int* in_sizes, int n_in,
                              void* d_out, int out_size, void* d_ws, size_t ws_size,
                              hipStream_t stream) {
  const float* x = (const float*)d_in[0];
  // d_in[1]=h, d_in[2]=w (fixed 256)
  const float* wqkv_w = (const float*)d_in[3];
  const float* wqkv_b = (const float*)d_in[4];
  const float* wp_w = (const float*)d_in[5];
  const float* wp_b = (const float*)d_in[6];
  const float* bias_table = (const float*)d_in[7];
  float* out = (float*)d_out;

  const size_t NEED = (size_t)(196608 + 65536) * sizeof(bf16);  // 524,288 B

  if (ws_size >= NEED) {
    bf16* wbf = (bf16*)d_ws;  // [0,196608) wqkv frag-order, [196608,262144) wp frag-order
    // Runtime spill guard: launch (256,3) variant only if it allocated zero scratch.
    static int use_hi = -1;
    if (use_hi < 0) {
      hipFuncAttributes attr{};
      const hipError_t e =
          hipFuncGetAttributes(&attr, reinterpret_cast<const void*>(&swin_v5_hi));
      use_hi = (e == hipSuccess && attr.localSizeBytes == 0) ? 1 : 0;
    }
    cvt_weights_v3<<<128, 256, 0, stream>>>(wqkv_w, wp_w, wbf);
    if (use_hi)
      swin_v5_hi<<<2048, 256, 0, stream>>>(x, wbf, wqkv_b, bias_table,
                                           wbf + 196608, wp_b, out);
    else
      swin_v5_lo<<<2048, 256, 0, stream>>>(x, wbf, wqkv_b, bias_table,
                                           wbf + 196608, wp_b, out);
  } else {
    fused_qkv_attn<<<2048, 256, 0, stream>>>(x, wqkv_w, wqkv_b, bias_table, out);
    proj_inplace<<<1024, 256, 0, stream>>>(out, wp_w, wp_b);
  }
}

// Round 6
// 465.122 us; speedup vs baseline: 1.1908x; 1.1908x over previous
//
#include <hip/hip_runtime.h>
#include <hip/hip_bf16.h>

// SpatialWindowSelfAttention — MI355X gfx950.
// v6 = v4 structure (proven 307us: ONE fused kernel, LDS-routed V, frag_xpose
// Q/K/P transposes, weights pre-permuted in ws) + register-lean phase split:
//   - Q-pass and K-pass separated (accQ 32 regs -> qf, freed; then accK 32)
//     instead of merged acc[4][4]=64.
//   - S^T/softmax/pa computed in qt-PAIRS (s2[4][2]=32 live) instead of
//     holding s[4][4]=64 through the whole softmax.
// Goal: true peak <168 VGPR so __launch_bounds__(256,3) gives 3 blocks/CU
// WITHOUT spilling (R2/R5 lesson: capping without shrinking state = spill).
// Runtime spill guard: launch the (256,3) twin only if localSizeBytes==0,
// else the plain-bounds twin (== v4-equivalent performance).
// v5 lesson (435us): shuffle-routed V on the PV critical path is a net loss;
// LDS round-trip for V both overlaps better AND frees registers. Reverted.
// Fallback path (ws too small): original verified two-kernel version.

typedef __bf16 bf16;
typedef bf16 bf16x2 __attribute__((ext_vector_type(2)));
typedef bf16 bf16x4 __attribute__((ext_vector_type(4)));
typedef bf16 bf16x8 __attribute__((ext_vector_type(8)));
typedef float f32x4 __attribute__((ext_vector_type(4)));
typedef int i32x4 __attribute__((ext_vector_type(4)));

#define MFMA16(a, b, c) __builtin_amdgcn_mfma_f32_16x16x32_bf16(a, b, c, 0, 0, 0)

__device__ __forceinline__ bf16x8 cvt8(const float* p) {  // 32B-aligned f32 -> bf16x8
  f32x4 lo = *(const f32x4*)p;
  f32x4 hi = *(const f32x4*)(p + 4);
  bf16x8 r;
#pragma unroll
  for (int j = 0; j < 4; j++) { r[j] = (bf16)lo[j]; r[j + 4] = (bf16)hi[j]; }
  return r;
}
__device__ __forceinline__ bf16x8 lds8(const bf16* p) {  // 8B-aligned LDS pair
  bf16x4 lo = *(const bf16x4*)p;
  bf16x4 hi = *(const bf16x4*)(p + 4);
  return __builtin_shufflevector(lo, hi, 0, 1, 2, 3, 4, 5, 6, 7);
}
__device__ __forceinline__ int pack2(float a, float b) {  // 2 f32 -> bf16x2 dword
  bf16x2 t; t[0] = (bf16)a; t[1] = (bf16)b;
  return __builtin_bit_cast(int, t);
}

// C-layout -> A/B-frag transform (verified v3/v4): dest lane (quad,lr) word w
// takes packed (r0,r1)/(r2,r3) pairs from source lane L0/L1 of tile lo/hi.
__device__ __forceinline__ bf16x8 frag_xpose(int aLo, int bLo, int aHi, int bHi,
                                             int L0, int L1, bool hiq) {
  const int a0 = __shfl(aLo, L0, 64), a1 = __shfl(aHi, L0, 64);
  const int b0 = __shfl(bLo, L0, 64), b1 = __shfl(bHi, L0, 64);
  const int a0h = __shfl(aLo, L1, 64), a1h = __shfl(aHi, L1, 64);
  const int b0h = __shfl(bLo, L1, 64), b1h = __shfl(bHi, L1, 64);
  const i32x4 w = {hiq ? a1 : a0, hiq ? b1 : b0, hiq ? a1h : a0h, hiq ? b1h : b0h};
  return __builtin_bit_cast(bf16x8, w);
}

// ======================= FAST PATH (v6) =======================

// K0: permute+convert weights into MFMA-fragment order.
// wqf entry (ct,kb,lane) @ dst[((ct*8+kb)*64+lane)*8] = wq[ct*16+(lane&15)][kb*32+(lane>>4)*8 ..+7]
__global__ __launch_bounds__(256) void cvt_weights_v3(
    const float* __restrict__ wq, const float* __restrict__ wp, bf16* __restrict__ dst) {
  const int did = blockIdx.x * 256 + threadIdx.x;  // [0, 32768)
  const float* src;
  bf16* o;
  if (did < 24576) {
    const int ct = did >> 9, rem = did & 511, kb = rem >> 6, ln = rem & 63;
    src = wq + (size_t)(ct * 16 + (ln & 15)) * 256 + kb * 32 + (ln >> 4) * 8;
    o = dst + (size_t)did * 8;
  } else {
    const int d2 = did - 24576;
    const int ct = d2 >> 9, rem = d2 & 511, kb = rem >> 6, ln = rem & 63;
    src = wp + (size_t)(ct * 16 + (ln & 15)) * 256 + kb * 32 + (ln >> 4) * 8;
    o = dst + 196608 + (size_t)d2 * 8;
  }
  *(bf16x8*)o = cvt8(src);
}

// One 2-tile projection pass: acc[2][4] over K=256, bias, -> frag_xpose'd frags.
// ct0 = first 16-ch weight tile, cb0 = first output channel (for bias).
__device__ __forceinline__ void proj2_frags(
    const int ct0, const int cb0, const int lane, const int lr, const int quad,
    const bf16 (*__restrict__ xs)[264], const bf16* __restrict__ wqf,
    const float* __restrict__ wqkv_b, const int L0, const int L1, const bool hiq,
    bf16x8* __restrict__ fr) {
  f32x4 acc[2][4] = {};
#pragma unroll
  for (int kb = 0; kb < 8; ++kb) {
    bf16x8 b[4];
#pragma unroll
    for (int nj = 0; nj < 4; ++nj) b[nj] = lds8(&xs[nj * 16 + lr][kb * 32 + quad * 8]);
#pragma unroll
    for (int mi = 0; mi < 2; ++mi) {
      const bf16x8 a = *(const bf16x8*)&wqf[(size_t)(((ct0 + mi) * 8 + kb) * 64 + lane) * 8];
#pragma unroll
      for (int nj = 0; nj < 4; ++nj) acc[mi][nj] = MFMA16(a, b[nj], acc[mi][nj]);
    }
  }
#pragma unroll
  for (int mi = 0; mi < 2; ++mi) {
    const f32x4 bb = *(const f32x4*)&wqkv_b[cb0 + mi * 16 + quad * 4];
#pragma unroll
    for (int nj = 0; nj < 4; ++nj)
#pragma unroll
      for (int r = 0; r < 4; ++r) acc[mi][nj][r] += bb[r];
  }
#pragma unroll
  for (int t = 0; t < 4; ++t)
    fr[t] = frag_xpose(pack2(acc[0][t][0], acc[0][t][1]), pack2(acc[0][t][2], acc[0][t][3]),
                       pack2(acc[1][t][0], acc[1][t][1]), pack2(acc[1][t][2], acc[1][t][3]),
                       L0, L1, hiq);
}

// Per-head attention, register-lean phase order. y packed into ob[16]
// (v4 layout: ob[(mt*2+ni)*2+w2], qtok on (quad,r), d on lr).
__device__ __forceinline__ void attn_head_v6(
    const int h, const int lane, const int lr, const int quad,
    const bf16 (*__restrict__ xs)[264], bf16* __restrict__ U,
    const bf16* __restrict__ wqf, const float* __restrict__ wqkv_b,
    const float* __restrict__ bias_table, int* __restrict__ ob) {
  const f32x4 zero = {0.f, 0.f, 0.f, 0.f};
  const float scale = 0.17677669529663687f;  // 1/sqrt(32)
  const int L0 = ((quad & 1) << 5) | lr, L1 = L0 + 16;
  const bool hiq = quad >= 2;

  // ---- Q pass (32-reg acc, freed), then K pass ----
  bf16x8 qf[4], kf[4];
  proj2_frags(2 * h, h * 32, lane, lr, quad, xs, wqf, wqkv_b, L0, L1, hiq, qf);
  proj2_frags(16 + 2 * h, 256 + h * 32, lane, lr, quad, xs, wqf, wqkv_b, L0, L1, hiq, kf);

  // ---- S^T + softmax + pa in qt-PAIRS (s2[4][2] = 32 regs live) ----
  bf16x8 pa[4][2];
#pragma unroll
  for (int qp = 0; qp < 2; ++qp) {
    f32x4 s2[4][2];
#pragma unroll
    for (int kt = 0; kt < 4; ++kt)
#pragma unroll
      for (int j = 0; j < 2; ++j) s2[kt][j] = MFMA16(kf[kt], qf[2 * qp + j], zero);
#pragma unroll
    for (int j = 0; j < 2; ++j) {
      const int qt = 2 * qp + j;
      const int qtok = qt * 16 + lr;
#pragma unroll
      for (int kt = 0; kt < 4; ++kt)
#pragma unroll
        for (int r = 0; r < 4; ++r) {
          const int ktok = kt * 16 + quad * 4 + r;
          const int idx = ((qtok >> 3) - (ktok >> 3) + 7) * 15 + (qtok & 7) - (ktok & 7) + 7;
          s2[kt][j][r] = s2[kt][j][r] * scale + bias_table[idx * 8 + h];
        }
      float mx = -1e30f;
#pragma unroll
      for (int kt = 0; kt < 4; ++kt)
#pragma unroll
        for (int r = 0; r < 4; ++r) mx = fmaxf(mx, s2[kt][j][r]);
      mx = fmaxf(mx, __shfl_xor(mx, 16, 64));
      mx = fmaxf(mx, __shfl_xor(mx, 32, 64));
      float sum = 0.f;
#pragma unroll
      for (int kt = 0; kt < 4; ++kt)
#pragma unroll
        for (int r = 0; r < 4; ++r) {
          const float e = __expf(s2[kt][j][r] - mx);
          s2[kt][j][r] = e;
          sum += e;
        }
      sum += __shfl_xor(sum, 16, 64);
      sum += __shfl_xor(sum, 32, 64);
      const float inv = 1.0f / sum;
#pragma unroll
      for (int kq = 0; kq < 2; ++kq)
        pa[qt][kq] = frag_xpose(
            pack2(s2[2 * kq][j][0] * inv, s2[2 * kq][j][1] * inv),
            pack2(s2[2 * kq][j][2] * inv, s2[2 * kq][j][3] * inv),
            pack2(s2[2 * kq + 1][j][0] * inv, s2[2 * kq + 1][j][1] * inv),
            pack2(s2[2 * kq + 1][j][2] * inv, s2[2 * kq + 1][j][3] * inv),
            L0, L1, hiq);
    }
  }

  // ---- V pass -> Vt LDS (v4 layout, stride 72); acc freed into LDS ----
  {
    f32x4 av[2][4] = {};
    const int ctv = 32 + 2 * h;
#pragma unroll
    for (int kb = 0; kb < 8; ++kb) {
      bf16x8 b[4];
#pragma unroll
      for (int nj = 0; nj < 4; ++nj) b[nj] = lds8(&xs[nj * 16 + lr][kb * 32 + quad * 8]);
#pragma unroll
      for (int mi = 0; mi < 2; ++mi) {
        const bf16x8 a = *(const bf16x8*)&wqf[(size_t)(((ctv + mi) * 8 + kb) * 64 + lane) * 8];
#pragma unroll
        for (int nj = 0; nj < 4; ++nj) av[mi][nj] = MFMA16(a, b[nj], av[mi][nj]);
      }
    }
#pragma unroll
    for (int mi = 0; mi < 2; ++mi) {
      const f32x4 bb = *(const f32x4*)&wqkv_b[512 + h * 32 + mi * 16 + quad * 4];
#pragma unroll
      for (int nj = 0; nj < 4; ++nj)
#pragma unroll
        for (int r = 0; r < 4; ++r)
          U[(mi * 16 + quad * 4 + r) * 72 + nj * 16 + lr] = (bf16)(av[mi][nj][r] + bb[r]);
    }
  }

  // ---- O = P @ V (v4) ----
  f32x4 o[4][2] = {};
#pragma unroll
  for (int kq = 0; kq < 2; ++kq) {
    bf16x8 vb[2];
#pragma unroll
    for (int ni = 0; ni < 2; ++ni) vb[ni] = lds8(&U[(ni * 16 + lr) * 72 + kq * 32 + quad * 8]);
#pragma unroll
    for (int mt = 0; mt < 4; ++mt)
#pragma unroll
      for (int ni = 0; ni < 2; ++ni) o[mt][ni] = MFMA16(pa[mt][kq], vb[ni], o[mt][ni]);
  }
  // pack y (bf16 pairs along r) into ob[16]
#pragma unroll
  for (int mt = 0; mt < 4; ++mt)
#pragma unroll
    for (int ni = 0; ni < 2; ++ni)
#pragma unroll
      for (int w2 = 0; w2 < 2; ++w2)
        ob[(mt * 2 + ni) * 2 + w2] = pack2(o[mt][ni][2 * w2], o[mt][ni][2 * w2 + 1]);
}

__device__ __forceinline__ void swin_v6_body(
    bf16 (*__restrict__ xs)[264], bf16 (*__restrict__ uni)[2304],
    const float* __restrict__ x, const bf16* __restrict__ wqf,
    const float* __restrict__ wqkv_b, const float* __restrict__ bias_table,
    const bf16* __restrict__ wpf, const float* __restrict__ wp_b,
    float* __restrict__ out) {
  const int tid = threadIdx.x;
  const int wave = tid >> 6, lane = tid & 63;
  const int lr = lane & 15, quad = lane >> 4;
  const int win = blockIdx.x;  // [0,2048)
  const int batch = win >> 10, wy = (win >> 5) & 31, wx = win & 31;
  const int base = batch * 65536 + wy * 2048 + wx * 8;
  bf16* const U = &uni[wave][0];

  // ---- stage full x window [64 tok][256 ch] f32 -> bf16 ----
  {
    const int tok = tid >> 2, cg = (tid & 3) * 64;
    const float* xp = x + (size_t)(base + ((tok >> 3) << 8) + (tok & 7)) * 256 + cg;
#pragma unroll
    for (int g = 0; g < 8; ++g) *(bf16x8*)&xs[tok][cg + g * 8] = cvt8(xp + g * 8);
  }
  __syncthreads();  // barrier 1

  int ob0[16], ob1[16];
  attn_head_v6(wave * 2 + 0, lane, lr, quad, (const bf16(*)[264])xs, U, wqf, wqkv_b,
               bias_table, ob0);
  attn_head_v6(wave * 2 + 1, lane, lr, quad, (const bf16(*)[264])xs, U, wqf, wqkv_b,
               bias_table, ob1);

  __syncthreads();  // barrier 2: all waves done reading x from xs
  // ---- write y (bf16) into xs[tok][ch] (v4 layout) ----
#pragma unroll
  for (int rep = 0; rep < 2; ++rep) {
    const int* ob = rep ? ob1 : ob0;
    const int hh = wave * 2 + rep;
#pragma unroll
    for (int mt = 0; mt < 4; ++mt)
#pragma unroll
      for (int ni = 0; ni < 2; ++ni)
#pragma unroll
        for (int w2 = 0; w2 < 2; ++w2) {
          const bf16x2 t = __builtin_bit_cast(bf16x2, ob[(mt * 2 + ni) * 2 + w2]);
#pragma unroll
          for (int e = 0; e < 2; ++e)
            xs[mt * 16 + quad * 4 + w2 * 2 + e][hh * 32 + ni * 16 + lr] = t[e];
        }
  }
  __syncthreads();  // barrier 3: y complete
  // ---- output projection: out = y @ wp^T + b; wave owns 64 cols ----
  f32x4 ap[4][4] = {};
#pragma unroll
  for (int kb = 0; kb < 8; ++kb) {
    bf16x8 a[4], b[4];
#pragma unroll
    for (int mt = 0; mt < 4; ++mt) a[mt] = lds8(&xs[mt * 16 + lr][kb * 32 + quad * 8]);
#pragma unroll
    for (int nt = 0; nt < 4; ++nt)
      b[nt] = *(const bf16x8*)&wpf[(size_t)(((wave * 4 + nt) * 8 + kb) * 64 + lane) * 8];
#pragma unroll
    for (int mt = 0; mt < 4; ++mt)
#pragma unroll
      for (int nt = 0; nt < 4; ++nt) ap[mt][nt] = MFMA16(a[mt], b[nt], ap[mt][nt]);
  }
#pragma unroll
  for (int nt = 0; nt < 4; ++nt) {
    const int col = (wave * 4 + nt) * 16 + lr;
    const float bv = wp_b[col];
#pragma unroll
    for (int mt = 0; mt < 4; ++mt)
#pragma unroll
      for (int r = 0; r < 4; ++r) {
        const int t = mt * 16 + quad * 4 + r;
        const size_t grow = (size_t)(base + ((t >> 3) << 8) + (t & 7));
        out[grow * 256 + col] = ap[mt][nt][r] + bv;
      }
  }
}

__global__ __launch_bounds__(256, 3) void swin_v6_hi(
    const float* __restrict__ x, const bf16* __restrict__ wqf,
    const float* __restrict__ wqkv_b, const float* __restrict__ bias_table,
    const bf16* __restrict__ wpf, const float* __restrict__ wp_b,
    float* __restrict__ out) {
  __shared__ __align__(16) bf16 xs[64][264];
  __shared__ __align__(16) bf16 uni[4][2304];
  swin_v6_body(xs, uni, x, wqf, wqkv_b, bias_table, wpf, wp_b, out);
}

__global__ __launch_bounds__(256) void swin_v6_lo(
    const float* __restrict__ x, const bf16* __restrict__ wqf,
    const float* __restrict__ wqkv_b, const float* __restrict__ bias_table,
    const bf16* __restrict__ wpf, const float* __restrict__ wp_b,
    float* __restrict__ out) {
  __shared__ __align__(16) bf16 xs[64][264];
  __shared__ __align__(16) bf16 uni[4][2304];
  swin_v6_body(xs, uni, x, wqf, wqkv_b, bias_table, wpf, wp_b, out);
}

// ======================= FALLBACK PATH (original verified kernels) =======================

#define QS_OFF 0
#define KS_OFF 2304
#define VT_OFF 4608
#define PL_OFF 0
#define UNI_SZ 6784

__global__ __launch_bounds__(256) void fused_qkv_attn(
    const float* __restrict__ x, const float* __restrict__ wqkv_w,
    const float* __restrict__ wqkv_b, const float* __restrict__ bias_table,
    float* __restrict__ out) {
  __shared__ bf16 xs[64][72];
  __shared__ bf16 uni[4][UNI_SZ];

  const int tid = threadIdx.x;
  const int wave = tid >> 6, lane = tid & 63;
  const int lr = lane & 15, quad = lane >> 4;
  const int win = blockIdx.x;
  const int batch = win >> 10, wy = (win >> 5) & 31, wx = win & 31;
  const int base = batch * 65536 + wy * 2048 + wx * 8;
  bf16* const U = &uni[wave][0];

  const f32x4 zero = {0.f, 0.f, 0.f, 0.f};
  const float scale = 0.17677669529663687f;

  for (int rep = 0; rep < 2; rep++) {
    const int h = wave * 2 + rep;
    const int cb[6] = {h * 32,       h * 32 + 16,
                       256 + h * 32, 256 + h * 32 + 16,
                       512 + h * 32, 512 + h * 32 + 16};

    f32x4 acc[4][6] = {};
    for (int kc = 0; kc < 4; kc++) {
      __syncthreads();
      {
        const int t = tid >> 2, c0 = (tid & 3) * 16;
        const float* xp = x + (size_t)(base + (t >> 3) * 256 + (t & 7)) * 256 + kc * 64 + c0;
        *(bf16x8*)&xs[t][c0] = cvt8(xp);
        *(bf16x8*)&xs[t][c0 + 8] = cvt8(xp + 8);
      }
      __syncthreads();
#pragma unroll
      for (int k2 = 0; k2 < 64; k2 += 32) {
        bf16x8 a[4], b[6];
#pragma unroll
        for (int mi = 0; mi < 4; mi++) a[mi] = lds8(&xs[mi * 16 + lr][k2 + quad * 8]);
#pragma unroll
        for (int nj = 0; nj < 6; nj++)
          b[nj] = cvt8(wqkv_w + (size_t)(cb[nj] + lr) * 256 + kc * 64 + k2 + quad * 8);
#pragma unroll
        for (int mi = 0; mi < 4; mi++)
#pragma unroll
          for (int nj = 0; nj < 6; nj++) acc[mi][nj] = MFMA16(a[mi], b[nj], acc[mi][nj]);
      }
    }

#pragma unroll
    for (int nj = 0; nj < 6; nj++) {
      const float bv = wqkv_b[cb[nj] + lr];
#pragma unroll
      for (int mi = 0; mi < 4; mi++)
#pragma unroll
        for (int r = 0; r < 4; r++) {
          const int tok = mi * 16 + quad * 4 + r;
          const float v = acc[mi][nj][r] + bv;
          if (nj < 2)      U[QS_OFF + tok * 36 + nj * 16 + lr] = (bf16)v;
          else if (nj < 4) U[KS_OFF + tok * 36 + (nj - 2) * 16 + lr] = (bf16)v;
          else             U[VT_OFF + ((nj - 4) * 16 + lr) * 68 + tok] = (bf16)v;
        }
    }

    bf16x8 qf[4], kf[4];
#pragma unroll
    for (int i = 0; i < 4; i++) {
      qf[i] = lds8(&U[QS_OFF + (i * 16 + lr) * 36 + quad * 8]);
      kf[i] = lds8(&U[KS_OFF + (i * 16 + lr) * 36 + quad * 8]);
    }
    f32x4 s[4][4];
#pragma unroll
    for (int mi = 0; mi < 4; mi++)
#pragma unroll
      for (int nj = 0; nj < 4; nj++) s[mi][nj] = MFMA16(qf[mi], kf[nj], zero);

#pragma unroll
    for (int mi = 0; mi < 4; mi++)
#pragma unroll
      for (int nj = 0; nj < 4; nj++)
#pragma unroll
        for (int r = 0; r < 4; r++) {
          const int qt = mi * 16 + quad * 4 + r;
          const int kt = nj * 16 + lr;
          const int idx = ((qt >> 3) - (kt >> 3) + 7) * 15 + ((qt & 7) - (kt & 7) + 7);
          s[mi][nj][r] = s[mi][nj][r] * scale + bias_table[idx * 8 + h];
        }

#pragma unroll
    for (int mi = 0; mi < 4; mi++)
#pragma unroll
      for (int r = 0; r < 4; r++) {
        float mx = -1e30f;
#pragma unroll
        for (int nj = 0; nj < 4; nj++) mx = fmaxf(mx, s[mi][nj][r]);
#pragma unroll
        for (int off = 1; off < 16; off <<= 1) mx = fmaxf(mx, __shfl_xor(mx, off, 64));
        float sum = 0.f;
#pragma unroll
        for (int nj = 0; nj < 4; nj++) {
          const float e = __expf(s[mi][nj][r] - mx);
          s[mi][nj][r] = e;
          sum += e;
        }
#pragma unroll
        for (int off = 1; off < 16; off <<= 1) sum += __shfl_xor(sum, off, 64);
        const float inv = 1.0f / sum;
#pragma unroll
        for (int nj = 0; nj < 4; nj++)
          U[PL_OFF + (mi * 16 + quad * 4 + r) * 68 + nj * 16 + lr] = (bf16)(s[mi][nj][r] * inv);
      }

    f32x4 o[4][2] = {};
#pragma unroll
    for (int kq = 0; kq < 2; kq++) {
      bf16x8 pa[4], vb[2];
#pragma unroll
      for (int mi = 0; mi < 4; mi++)
        pa[mi] = lds8(&U[PL_OFF + (mi * 16 + lr) * 68 + kq * 32 + quad * 8]);
#pragma unroll
      for (int ni = 0; ni < 2; ni++)
        vb[ni] = lds8(&U[VT_OFF + (ni * 16 + lr) * 68 + kq * 32 + quad * 8]);
#pragma unroll
      for (int mi = 0; mi < 4; mi++)
#pragma unroll
        for (int ni = 0; ni < 2; ni++) o[mi][ni] = MFMA16(pa[mi], vb[ni], o[mi][ni]);
    }

#pragma unroll
    for (int mi = 0; mi < 4; mi++)
#pragma unroll
      for (int ni = 0; ni < 2; ni++)
#pragma unroll
        for (int r = 0; r < 4; r++) {
          const int t = mi * 16 + quad * 4 + r;
          const size_t row = (size_t)(base + (t >> 3) * 256 + (t & 7));
          out[row * 256 + h * 32 + ni * 16 + lr] = o[mi][ni][r];
        }
  }
}

__global__ __launch_bounds__(256) void proj_inplace(
    float* io, const float* __restrict__ W, const float* __restrict__ bias) {
  const int tid = threadIdx.x;
  const int wave = tid >> 6, lane = tid & 63;
  const int lr = lane & 15, quad = lane >> 4;
  const int row0 = blockIdx.x * 128 + (wave >> 1) * 64;
  const int col0 = (wave & 1) * 128;

  f32x4 acc[4][8] = {};
#pragma unroll
  for (int kk = 0; kk < 256; kk += 32) {
    bf16x8 a[4], b[8];
#pragma unroll
    for (int mi = 0; mi < 4; mi++)
      a[mi] = cvt8(io + (size_t)(row0 + mi * 16 + lr) * 256 + kk + quad * 8);
#pragma unroll
    for (int nj = 0; nj < 8; nj++)
      b[nj] = cvt8(W + (size_t)(col0 + nj * 16 + lr) * 256 + kk + quad * 8);
#pragma unroll
    for (int mi = 0; mi < 4; mi++)
#pragma unroll
      for (int nj = 0; nj < 8; nj++) acc[mi][nj] = MFMA16(a[mi], b[nj], acc[mi][nj]);
  }
  __syncthreads();
#pragma unroll
  for (int mi = 0; mi < 4; mi++)
#pragma unroll
    for (int nj = 0; nj < 8; nj++) {
      const int col = col0 + nj * 16 + lr;
      const float bv = bias[col];
#pragma unroll
      for (int r = 0; r < 4; r++) {
        const int row = row0 + mi * 16 + quad * 4 + r;
        io[(size_t)row * 256 + col] = acc[mi][nj][r] + bv;
      }
    }
}

extern "C" void kernel_launch(void* const* d_in, const int* in_sizes, int n_in,
                              void* d_out, int out_size, void* d_ws, size_t ws_size,
                              hipStream_t stream) {
  const float* x = (const float*)d_in[0];
  // d_in[1]=h, d_in[2]=w (fixed 256)
  const float* wqkv_w = (const float*)d_in[3];
  const float* wqkv_b = (const float*)d_in[4];
  const float* wp_w = (const float*)d_in[5];
  const float* wp_b = (const float*)d_in[6];
  const float* bias_table = (const float*)d_in[7];
  float* out = (float*)d_out;

  const size_t NEED = (size_t)(196608 + 65536) * sizeof(bf16);  // 524,288 B

  if (ws_size >= NEED) {
    bf16* wbf = (bf16*)d_ws;  // [0,196608) wqkv frag-order, [196608,262144) wp frag-order
    // Runtime spill guard: launch the (256,3) twin only if it allocated zero scratch.
    static int use_hi = -1;
    if (use_hi < 0) {
      hipFuncAttributes attr{};
      const hipError_t e =
          hipFuncGetAttributes(&attr, reinterpret_cast<const void*>(&swin_v6_hi));
      use_hi = (e == hipSuccess && attr.localSizeBytes == 0) ? 1 : 0;
    }
    cvt_weights_v3<<<128, 256, 0, stream>>>(wqkv_w, wp_w, wbf);
    if (use_hi)
      swin_v6_hi<<<2048, 256, 0, stream>>>(x, wbf, wqkv_b, bias_table,
                                           wbf + 196608, wp_b, out);
    else
      swin_v6_lo<<<2048, 256, 0, stream>>>(x, wbf, wqkv_b, bias_table,
                                           wbf + 196608, wp_b, out);
  } else {
    fused_qkv_attn<<<2048, 256, 0, stream>>>(x, wqkv_w, wqkv_b, bias_table, out);
    proj_inplace<<<1024, 256, 0, stream>>>(out, wp_w, wp_b);
  }
}